// Round 1
// baseline (851.106 us; speedup 1.0000x reference)
//
#include <hip/hip_runtime.h>
#include <hip/hip_bf16.h>

#define T_NODES (64 * 2048)   // G*N = 131072
#define CIN 64
#define HC 128                // HEADS * C_OUT
#define NEG_SLOPE 0.2f

// ---- monotone key encoding for float atomicMax on unsigned ----
__device__ __forceinline__ unsigned fkey(float f) {
    unsigned b = __float_as_uint(f);
    return b ^ (unsigned)(((int)b >> 31) | 0x80000000);
}
__device__ __forceinline__ float funkey(unsigned k) {
    unsigned b = (k & 0x80000000u) ? (k ^ 0x80000000u) : ~k;
    return __uint_as_float(b);
}

// ---- Kernel A: xl = x@W_l, xr = x@W_r (fused). 32 rows x 256 cols per block.
// cols 0..127 -> xl (W_l), 128..255 -> xr (W_r).
__global__ __launch_bounds__(256) void gemm_lr(const float* __restrict__ x,
                                               const float* __restrict__ Wl,
                                               const float* __restrict__ Wr,
                                               float* __restrict__ xl,
                                               float* __restrict__ xr) {
    __shared__ float xsT[CIN][32];   // transposed x tile: [k][row]
    const int row0 = blockIdx.x * 32;
    const int tid  = threadIdx.x;

    // stage x[row0..row0+31][0..63] transposed into LDS
    {
        const int r  = tid >> 3;        // 0..31
        const int k0 = (tid & 7) * 8;   // 0..56
        const float4* xp = (const float4*)(x + (size_t)(row0 + r) * CIN + k0);
        float4 a = xp[0], b = xp[1];
        xsT[k0 + 0][r] = a.x; xsT[k0 + 1][r] = a.y;
        xsT[k0 + 2][r] = a.z; xsT[k0 + 3][r] = a.w;
        xsT[k0 + 4][r] = b.x; xsT[k0 + 5][r] = b.y;
        xsT[k0 + 6][r] = b.z; xsT[k0 + 7][r] = b.w;
    }
    __syncthreads();

    const int cg = tid & 31;          // col group -> c0 = cg*8 in [0,256)
    const int rg = tid >> 5;          // row group -> r0 = rg*4
    const int c0 = cg * 8;
    const int r0 = rg * 4;
    const float* Wp = (c0 < HC) ? Wl : Wr;
    const int cc = c0 & (HC - 1);

    float acc[4][8];
#pragma unroll
    for (int i = 0; i < 4; i++)
#pragma unroll
        for (int j = 0; j < 8; j++) acc[i][j] = 0.f;

#pragma unroll 4
    for (int k = 0; k < CIN; k++) {
        float4 xv = *(const float4*)&xsT[k][r0];
        float4 w0 = *(const float4*)(Wp + k * HC + cc);
        float4 w1 = *(const float4*)(Wp + k * HC + cc + 4);
        const float xs[4] = {xv.x, xv.y, xv.z, xv.w};
#pragma unroll
        for (int i = 0; i < 4; i++) {
            acc[i][0] += xs[i] * w0.x; acc[i][1] += xs[i] * w0.y;
            acc[i][2] += xs[i] * w0.z; acc[i][3] += xs[i] * w0.w;
            acc[i][4] += xs[i] * w1.x; acc[i][5] += xs[i] * w1.y;
            acc[i][6] += xs[i] * w1.z; acc[i][7] += xs[i] * w1.w;
        }
    }

    float* op = (c0 < HC) ? xl : xr;
#pragma unroll
    for (int i = 0; i < 4; i++) {
        float4 s0 = {acc[i][0], acc[i][1], acc[i][2], acc[i][3]};
        float4 s1 = {acc[i][4], acc[i][5], acc[i][6], acc[i][7]};
        float* dst = op + (size_t)(row0 + r0 + i) * HC + cc;
        *(float4*)(dst)     = s0;
        *(float4*)(dst + 4) = s1;
    }
}

// ---- init out with broadcast bias ----
__global__ void init_out(float* __restrict__ out, const float* __restrict__ bias,
                         int total4) {
    int i = blockIdx.x * blockDim.x + threadIdx.x;
    if (i < total4) {
        ((float4*)out)[i] = ((const float4*)bias)[i & 31];
    }
}

// ---- Kernel B: per-edge score (both heads) + atomic max per (dst, head) ----
// one wave (64 lanes) per edge
__global__ __launch_bounds__(256) void edge_score(const float* __restrict__ xl,
                                                  const float* __restrict__ xr,
                                                  const int* __restrict__ ei,
                                                  const float* __restrict__ att,
                                                  float* __restrict__ sc,
                                                  unsigned* __restrict__ mkey,
                                                  int E, int ET) {
    int gtid = blockIdx.x * 256 + threadIdx.x;
    int w = gtid >> 6;
    int lane = threadIdx.x & 63;
    if (w >= ET) return;
    int src, dst;
    if (w < E) { src = ei[w]; dst = ei[E + w]; }
    else       { src = w - E; dst = src; }

    float a0 = xl[(size_t)src * HC + lane];
    float a1 = xl[(size_t)src * HC + 64 + lane];
    float b0 = xr[(size_t)dst * HC + lane];
    float b1 = xr[(size_t)dst * HC + 64 + lane];
    float h0 = a0 + b0; h0 = (h0 > 0.f) ? h0 : NEG_SLOPE * h0;
    float h1 = a1 + b1; h1 = (h1 > 0.f) ? h1 : NEG_SLOPE * h1;
    float p0 = att[lane] * h0;
    float p1 = att[64 + lane] * h1;
#pragma unroll
    for (int off = 32; off; off >>= 1) {
        p0 += __shfl_xor(p0, off);
        p1 += __shfl_xor(p1, off);
    }
    if (lane == 0) {
        sc[(size_t)w * 2]     = p0;
        sc[(size_t)w * 2 + 1] = p1;
        atomicMax(&mkey[dst * 2],     fkey(p0));
        atomicMax(&mkey[dst * 2 + 1], fkey(p1));
    }
}

// ---- Kernel C: ealpha = exp(score - m[dst]); denom[dst] += ealpha ----
__global__ void edge_exp(float* __restrict__ sc, const unsigned* __restrict__ mkey,
                         float* __restrict__ denom, const int* __restrict__ ei,
                         int E, int ET) {
    int i = blockIdx.x * blockDim.x + threadIdx.x;
    if (i >= 2 * ET) return;
    int e = i >> 1, h = i & 1;
    int dst = (e < E) ? ei[E + e] : (e - E);
    float m = funkey(mkey[dst * 2 + h]);
    float v = expf(sc[i] - m);
    sc[i] = v;
    atomicAdd(&denom[dst * 2 + h], v);
}

// ---- Kernel D: out[dst] += (ealpha/denom[dst]) * xl[src] ----
// one wave per edge, 2 atomics per lane (head0 col lane, head1 col lane)
__global__ __launch_bounds__(256) void edge_aggr(const float* __restrict__ xl,
                                                 const float* __restrict__ sc,
                                                 const float* __restrict__ denom,
                                                 const int* __restrict__ ei,
                                                 float* __restrict__ out,
                                                 int E, int ET) {
    int gtid = blockIdx.x * 256 + threadIdx.x;
    int w = gtid >> 6;
    int lane = threadIdx.x & 63;
    if (w >= ET) return;
    int src, dst;
    if (w < E) { src = ei[w]; dst = ei[E + w]; }
    else       { src = w - E; dst = src; }

    float al0 = sc[(size_t)w * 2]     / denom[dst * 2];
    float al1 = sc[(size_t)w * 2 + 1] / denom[dst * 2 + 1];
    atomicAdd(out + (size_t)dst * HC + lane,      al0 * xl[(size_t)src * HC + lane]);
    atomicAdd(out + (size_t)dst * HC + 64 + lane, al1 * xl[(size_t)src * HC + 64 + lane]);
}

extern "C" void kernel_launch(void* const* d_in, const int* in_sizes, int n_in,
                              void* d_out, int out_size, void* d_ws, size_t ws_size,
                              hipStream_t stream) {
    const float* x    = (const float*)d_in[0];
    const int*   ei   = (const int*)d_in[1];
    const float* Wl   = (const float*)d_in[2];
    const float* Wr   = (const float*)d_in[3];
    const float* att  = (const float*)d_in[4];
    const float* bias = (const float*)d_in[5];
    float* out = (float*)d_out;

    const int E  = in_sizes[1] / 2;
    const int ET = E + T_NODES;

    // workspace layout (f32 unless noted)
    float* xl = (float*)d_ws;                        // T*128
    float* xr = xl + (size_t)T_NODES * HC;           // T*128
    float* sc = xr + (size_t)T_NODES * HC;           // ET*2 (scores -> ealpha)
    unsigned* mkey = (unsigned*)(sc + (size_t)ET * 2);  // T*2
    float* denom = (float*)(mkey + (size_t)T_NODES * 2); // T*2

    hipMemsetAsync(mkey, 0, (size_t)T_NODES * 2 * sizeof(unsigned), stream);
    hipMemsetAsync(denom, 0, (size_t)T_NODES * 2 * sizeof(float), stream);

    gemm_lr<<<T_NODES / 32, 256, 0, stream>>>(x, Wl, Wr, xl, xr);
    init_out<<<(T_NODES * 32 + 255) / 256, 256, 0, stream>>>(out, bias, T_NODES * 32);

    int wave_blocks = (ET + 3) / 4;   // 4 waves (edges) per 256-thread block
    edge_score<<<wave_blocks, 256, 0, stream>>>(xl, xr, ei, att, sc, mkey, E, ET);
    edge_exp<<<(2 * ET + 255) / 256, 256, 0, stream>>>(sc, mkey, denom, ei, E, ET);
    edge_aggr<<<wave_blocks, 256, 0, stream>>>(xl, sc, denom, ei, out, E, ET);
}

// Round 2
// 362.745 us; speedup vs baseline: 2.3463x; 2.3463x over previous
//
#include <hip/hip_runtime.h>
#include <hip/hip_bf16.h>

#define T_NODES (64 * 2048)   // G*N = 131072
#define CIN 64
#define HC 128                // HEADS * C_OUT
#define NEG_SLOPE 0.2f

// ---- Kernel A: xl = x@W_l, xr = x@W_r (fused). 32 rows x 256 cols per block.
__global__ __launch_bounds__(256) void gemm_lr(const float* __restrict__ x,
                                               const float* __restrict__ Wl,
                                               const float* __restrict__ Wr,
                                               float* __restrict__ xl,
                                               float* __restrict__ xr) {
    __shared__ float xsT[CIN][32];   // transposed x tile: [k][row]
    const int row0 = blockIdx.x * 32;
    const int tid  = threadIdx.x;

    {
        const int r  = tid >> 3;        // 0..31
        const int k0 = (tid & 7) * 8;   // 0..56
        const float4* xp = (const float4*)(x + (size_t)(row0 + r) * CIN + k0);
        float4 a = xp[0], b = xp[1];
        xsT[k0 + 0][r] = a.x; xsT[k0 + 1][r] = a.y;
        xsT[k0 + 2][r] = a.z; xsT[k0 + 3][r] = a.w;
        xsT[k0 + 4][r] = b.x; xsT[k0 + 5][r] = b.y;
        xsT[k0 + 6][r] = b.z; xsT[k0 + 7][r] = b.w;
    }
    __syncthreads();

    const int cg = tid & 31;          // col group -> c0 = cg*8 in [0,256)
    const int rg = tid >> 5;          // row group -> r0 = rg*4
    const int c0 = cg * 8;
    const int r0 = rg * 4;
    const float* Wp = (c0 < HC) ? Wl : Wr;
    const int cc = c0 & (HC - 1);

    float acc[4][8];
#pragma unroll
    for (int i = 0; i < 4; i++)
#pragma unroll
        for (int j = 0; j < 8; j++) acc[i][j] = 0.f;

#pragma unroll 4
    for (int k = 0; k < CIN; k++) {
        float4 xv = *(const float4*)&xsT[k][r0];
        float4 w0 = *(const float4*)(Wp + k * HC + cc);
        float4 w1 = *(const float4*)(Wp + k * HC + cc + 4);
        const float xs[4] = {xv.x, xv.y, xv.z, xv.w};
#pragma unroll
        for (int i = 0; i < 4; i++) {
            acc[i][0] += xs[i] * w0.x; acc[i][1] += xs[i] * w0.y;
            acc[i][2] += xs[i] * w0.z; acc[i][3] += xs[i] * w0.w;
            acc[i][4] += xs[i] * w1.x; acc[i][5] += xs[i] * w1.y;
            acc[i][6] += xs[i] * w1.z; acc[i][7] += xs[i] * w1.w;
        }
    }

    float* op = (c0 < HC) ? xl : xr;
#pragma unroll
    for (int i = 0; i < 4; i++) {
        float4 s0 = {acc[i][0], acc[i][1], acc[i][2], acc[i][3]};
        float4 s1 = {acc[i][4], acc[i][5], acc[i][6], acc[i][7]};
        float* dst = op + (size_t)(row0 + r0 + i) * HC + cc;
        *(float4*)(dst)     = s0;
        *(float4*)(dst + 4) = s1;
    }
}

// ---- counting-sort step 1: histogram of dst ----
__global__ void hist_dst(const int* __restrict__ ei, unsigned* __restrict__ counts,
                         int E, int ET) {
    int i = blockIdx.x * 256 + threadIdx.x;
    if (i >= ET) return;
    int dst = (i < E) ? ei[E + i] : (i - E);
    atomicAdd(&counts[dst], 1u);
}

// ---- step 2a: per-tile (1024 entries) exclusive scan; tile sums to partials ----
__global__ __launch_bounds__(256) void scan_tiles(const unsigned* __restrict__ counts,
                                                  unsigned* __restrict__ offs,
                                                  unsigned* __restrict__ partials) {
    __shared__ unsigned s[256];
    const int t = threadIdx.x;
    const int base = blockIdx.x * 1024 + t * 4;
    uint4 c = *(const uint4*)(counts + base);
    unsigned mysum = c.x + c.y + c.z + c.w;
    s[t] = mysum;
    __syncthreads();
    for (int off = 1; off < 256; off <<= 1) {
        unsigned v = (t >= off) ? s[t - off] : 0u;
        __syncthreads();
        s[t] += v;
        __syncthreads();
    }
    unsigned excl = s[t] - mysum;
    uint4 o;
    o.x = excl;
    o.y = excl + c.x;
    o.z = o.y + c.y;
    o.w = o.z + c.z;
    *(uint4*)(offs + base) = o;
    if (t == 255) partials[blockIdx.x] = s[255];
}

// ---- step 2b: exclusive scan of the 128 tile sums (single block) ----
__global__ void scan_partials(unsigned* __restrict__ partials) {
    __shared__ unsigned s[128];
    int t = threadIdx.x;
    unsigned v = partials[t];
    s[t] = v;
    __syncthreads();
    for (int off = 1; off < 128; off <<= 1) {
        unsigned u = (t >= off) ? s[t - off] : 0u;
        __syncthreads();
        s[t] += u;
        __syncthreads();
    }
    partials[t] = s[t] - v;   // exclusive
}

// ---- step 2c: add tile bases; produce final offsets + mutable cursors ----
__global__ void finalize_offs(unsigned* __restrict__ offs,
                              const unsigned* __restrict__ partials,
                              unsigned* __restrict__ cursor) {
    int i = blockIdx.x * 256 + threadIdx.x;
    unsigned v = offs[i] + partials[i >> 10];
    offs[i] = v;
    cursor[i] = v;
}

// ---- step 3: scatter src ids into dst-sorted order ----
__global__ void scatter_edges(const int* __restrict__ ei, unsigned* __restrict__ cursor,
                              int* __restrict__ sorted_src, int E, int ET) {
    int i = blockIdx.x * 256 + threadIdx.x;
    if (i >= ET) return;
    int src, dst;
    if (i < E) { src = ei[i]; dst = ei[E + i]; }
    else       { src = dst = i - E; }
    unsigned pos = atomicAdd(&cursor[dst], 1u);
    sorted_src[pos] = src;
}

// ---- Kernel B: fused score + online-softmax + aggregate. One wave per node. ----
__global__ __launch_bounds__(256) void fused_aggr(const float* __restrict__ xl,
                                                  const float* __restrict__ xr,
                                                  const int* __restrict__ sorted_src,
                                                  const unsigned* __restrict__ offs,
                                                  const unsigned* __restrict__ counts,
                                                  const float* __restrict__ att,
                                                  const float* __restrict__ bias,
                                                  float* __restrict__ out) {
    const int lane = threadIdx.x & 63;
    int node = (blockIdx.x * 256 + threadIdx.x) >> 6;
    node = __builtin_amdgcn_readfirstlane(node);

    const float att0 = att[lane], att1 = att[64 + lane];
    const float xr0 = xr[(size_t)node * HC + lane];
    const float xr1 = xr[(size_t)node * HC + 64 + lane];

    const int start = (int)offs[node];
    const int cnt   = (int)counts[node];

    float m0 = -INFINITY, m1 = -INFINITY;
    float d0 = 0.f, d1 = 0.f, acc0 = 0.f, acc1 = 0.f;

    for (int k = 0; k < cnt; ++k) {
        const int src = sorted_src[start + k];
        const float a0 = xl[(size_t)src * HC + lane];
        const float a1 = xl[(size_t)src * HC + 64 + lane];
        float h0 = a0 + xr0; h0 = h0 > 0.f ? h0 : NEG_SLOPE * h0;
        float h1 = a1 + xr1; h1 = h1 > 0.f ? h1 : NEG_SLOPE * h1;
        float p0 = att0 * h0, p1 = att1 * h1;
#pragma unroll
        for (int off = 32; off; off >>= 1) {
            p0 += __shfl_xor(p0, off);
            p1 += __shfl_xor(p1, off);
        }
        float nm0 = fmaxf(m0, p0), nm1 = fmaxf(m1, p1);
        float sc0 = __expf(m0 - nm0), sc1 = __expf(m1 - nm1);
        float e0  = __expf(p0 - nm0), e1  = __expf(p1 - nm1);
        d0 = d0 * sc0 + e0;            d1 = d1 * sc1 + e1;
        acc0 = acc0 * sc0 + e0 * a0;   acc1 = acc1 * sc1 + e1 * a1;
        m0 = nm0; m1 = nm1;
    }

    out[(size_t)node * HC + lane]      = acc0 / d0 + bias[lane];
    out[(size_t)node * HC + 64 + lane] = acc1 / d1 + bias[64 + lane];
}

extern "C" void kernel_launch(void* const* d_in, const int* in_sizes, int n_in,
                              void* d_out, int out_size, void* d_ws, size_t ws_size,
                              hipStream_t stream) {
    const float* x    = (const float*)d_in[0];
    const int*   ei   = (const int*)d_in[1];
    const float* Wl   = (const float*)d_in[2];
    const float* Wr   = (const float*)d_in[3];
    const float* att  = (const float*)d_in[4];
    const float* bias = (const float*)d_in[5];
    float* out = (float*)d_out;

    const int E  = in_sizes[1] / 2;
    const int ET = E + T_NODES;

    // workspace layout
    float* xl = (float*)d_ws;                              // T*128 f32
    float* xr = xl + (size_t)T_NODES * HC;                 // T*128 f32
    int* sorted_src = (int*)(xr + (size_t)T_NODES * HC);   // ET int
    unsigned* counts   = (unsigned*)(sorted_src + ET);     // T
    unsigned* offs     = counts + T_NODES;                 // T
    unsigned* cursor   = offs + T_NODES;                   // T
    unsigned* partials = cursor + T_NODES;                 // 128

    hipMemsetAsync(counts, 0, (size_t)T_NODES * sizeof(unsigned), stream);

    gemm_lr<<<T_NODES / 32, 256, 0, stream>>>(x, Wl, Wr, xl, xr);

    int eblocks = (ET + 255) / 256;
    hist_dst<<<eblocks, 256, 0, stream>>>(ei, counts, E, ET);
    scan_tiles<<<T_NODES / 1024, 256, 0, stream>>>(counts, offs, partials);
    scan_partials<<<1, 128, 0, stream>>>(partials);
    finalize_offs<<<T_NODES / 256, 256, 0, stream>>>(offs, partials, cursor);
    scatter_edges<<<eblocks, 256, 0, stream>>>(ei, cursor, sorted_src, E, ET);

    fused_aggr<<<T_NODES / 4, 256, 0, stream>>>(xl, xr, sorted_src, offs, counts,
                                                att, bias, out);
}

// Round 3
// 285.956 us; speedup vs baseline: 2.9763x; 1.2685x over previous
//
#include <hip/hip_runtime.h>
#include <hip/hip_bf16.h>

#define T_NODES (64 * 2048)   // G*N = 131072
#define CIN 64
#define HC 128                // HEADS * C_OUT
#define NEG_SLOPE 0.2f

typedef unsigned short ushort_t;

__device__ __forceinline__ ushort_t f2bf(float x) {
    unsigned u = __float_as_uint(x);
    u += 0x7fffu + ((u >> 16) & 1u);   // RNE
    return (ushort_t)(u >> 16);
}
__device__ __forceinline__ float bf2f(ushort_t b) {
    return __uint_as_float(((unsigned)b) << 16);
}

// ---- Kernel A: xl = x@W_l, xr = x@W_r (fused), bf16 outputs. ----
// 32 rows x 256 cols per block; cols 0..127 -> xl, 128..255 -> xr.
__global__ __launch_bounds__(256) void gemm_lr(const float* __restrict__ x,
                                               const float* __restrict__ Wl,
                                               const float* __restrict__ Wr,
                                               ushort_t* __restrict__ xl,
                                               ushort_t* __restrict__ xr) {
    __shared__ float xsT[CIN][32];   // transposed x tile: [k][row]
    const int row0 = blockIdx.x * 32;
    const int tid  = threadIdx.x;

    {
        const int r  = tid >> 3;        // 0..31
        const int k0 = (tid & 7) * 8;   // 0..56
        const float4* xp = (const float4*)(x + (size_t)(row0 + r) * CIN + k0);
        float4 a = xp[0], b = xp[1];
        xsT[k0 + 0][r] = a.x; xsT[k0 + 1][r] = a.y;
        xsT[k0 + 2][r] = a.z; xsT[k0 + 3][r] = a.w;
        xsT[k0 + 4][r] = b.x; xsT[k0 + 5][r] = b.y;
        xsT[k0 + 6][r] = b.z; xsT[k0 + 7][r] = b.w;
    }
    __syncthreads();

    const int cg = tid & 31;          // col group -> c0 = cg*8 in [0,256)
    const int rg = tid >> 5;          // row group -> r0 = rg*4
    const int c0 = cg * 8;
    const int r0 = rg * 4;
    const float* Wp = (c0 < HC) ? Wl : Wr;
    const int cc = c0 & (HC - 1);

    float acc[4][8];
#pragma unroll
    for (int i = 0; i < 4; i++)
#pragma unroll
        for (int j = 0; j < 8; j++) acc[i][j] = 0.f;

#pragma unroll 4
    for (int k = 0; k < CIN; k++) {
        float4 xv = *(const float4*)&xsT[k][r0];
        float4 w0 = *(const float4*)(Wp + k * HC + cc);
        float4 w1 = *(const float4*)(Wp + k * HC + cc + 4);
        const float xs[4] = {xv.x, xv.y, xv.z, xv.w};
#pragma unroll
        for (int i = 0; i < 4; i++) {
            acc[i][0] += xs[i] * w0.x; acc[i][1] += xs[i] * w0.y;
            acc[i][2] += xs[i] * w0.z; acc[i][3] += xs[i] * w0.w;
            acc[i][4] += xs[i] * w1.x; acc[i][5] += xs[i] * w1.y;
            acc[i][6] += xs[i] * w1.z; acc[i][7] += xs[i] * w1.w;
        }
    }

    ushort_t* op = (c0 < HC) ? xl : xr;
#pragma unroll
    for (int i = 0; i < 4; i++) {
        union { ushort_t u[8]; uint4 v; } pk;
#pragma unroll
        for (int j = 0; j < 8; j++) pk.u[j] = f2bf(acc[i][j]);
        *(uint4*)(op + (size_t)(row0 + r0 + i) * HC + cc) = pk.v;
    }
}

// ---- counting-sort step 1: histogram of dst ----
__global__ void hist_dst(const int* __restrict__ ei, unsigned* __restrict__ counts,
                         int E, int ET) {
    int i = blockIdx.x * 256 + threadIdx.x;
    if (i >= ET) return;
    int dst = (i < E) ? ei[E + i] : (i - E);
    atomicAdd(&counts[dst], 1u);
}

// ---- step 2a: per-tile (1024 entries) exclusive scan; tile sums -> partials ----
__global__ __launch_bounds__(256) void scan_tiles(const unsigned* __restrict__ counts,
                                                  unsigned* __restrict__ offs,
                                                  unsigned* __restrict__ partials) {
    __shared__ unsigned s[256];
    const int t = threadIdx.x;
    const int base = blockIdx.x * 1024 + t * 4;
    uint4 c = *(const uint4*)(counts + base);
    unsigned mysum = c.x + c.y + c.z + c.w;
    s[t] = mysum;
    __syncthreads();
    for (int off = 1; off < 256; off <<= 1) {
        unsigned v = (t >= off) ? s[t - off] : 0u;
        __syncthreads();
        s[t] += v;
        __syncthreads();
    }
    unsigned excl = s[t] - mysum;
    uint4 o;
    o.x = excl;
    o.y = excl + c.x;
    o.z = o.y + c.y;
    o.w = o.z + c.z;
    *(uint4*)(offs + base) = o;
    if (t == 255) partials[blockIdx.x] = s[255];
}

// ---- step 2b: exclusive scan of the 128 tile sums ----
__global__ void scan_partials(unsigned* __restrict__ partials) {
    __shared__ unsigned s[128];
    int t = threadIdx.x;
    unsigned v = partials[t];
    s[t] = v;
    __syncthreads();
    for (int off = 1; off < 128; off <<= 1) {
        unsigned u = (t >= off) ? s[t - off] : 0u;
        __syncthreads();
        s[t] += u;
        __syncthreads();
    }
    partials[t] = s[t] - v;   // exclusive
}

// ---- step 2c: add tile bases; final offsets + mutable cursors ----
__global__ void finalize_offs(unsigned* __restrict__ offs,
                              const unsigned* __restrict__ partials,
                              unsigned* __restrict__ cursor) {
    int i = blockIdx.x * 256 + threadIdx.x;
    unsigned v = offs[i] + partials[i >> 10];
    offs[i] = v;
    cursor[i] = v;
}

// ---- step 3: scatter src ids into dst-sorted order ----
__global__ void scatter_edges(const int* __restrict__ ei, unsigned* __restrict__ cursor,
                              int* __restrict__ sorted_src, int E, int ET) {
    int i = blockIdx.x * 256 + threadIdx.x;
    if (i >= ET) return;
    int src, dst;
    if (i < E) { src = ei[i]; dst = ei[E + i]; }
    else       { src = dst = i - E; }
    unsigned pos = atomicAdd(&cursor[dst], 1u);
    sorted_src[pos] = src;
}

// ---- Kernel B: fused score + online-softmax + aggregate. One wave per node. ----
// Lane owns cols {2*lane, 2*lane+1}; lanes 0-31 = head 0, lanes 32-63 = head 1.
__global__ __launch_bounds__(256) void fused_aggr(const ushort_t* __restrict__ xl,
                                                  const ushort_t* __restrict__ xr,
                                                  const int* __restrict__ sorted_src,
                                                  const unsigned* __restrict__ offs,
                                                  const unsigned* __restrict__ counts,
                                                  const float* __restrict__ att,
                                                  const float* __restrict__ bias,
                                                  float* __restrict__ out) {
    const int lane = threadIdx.x & 63;
    int node = (blockIdx.x * 256 + threadIdx.x) >> 6;
    node = __builtin_amdgcn_readfirstlane(node);

    const float2 att2 = ((const float2*)att)[lane];
    const ushort2 xrv = ((const ushort2*)xr)[(size_t)node * 64 + lane];
    const float xr0 = bf2f(xrv.x), xr1 = bf2f(xrv.y);

    const int start = (int)offs[node];
    const int cnt   = (int)counts[node];
    const ushort2* xl2 = (const ushort2*)xl;

    float m = -INFINITY, d = 0.f, acc0 = 0.f, acc1 = 0.f;

#define SCORE(a0, a1, p)                                                    \
    {                                                                       \
        float h0 = (a0) + xr0; h0 = h0 > 0.f ? h0 : NEG_SLOPE * h0;         \
        float h1 = (a1) + xr1; h1 = h1 > 0.f ? h1 : NEG_SLOPE * h1;         \
        p = att2.x * h0 + att2.y * h1;                                      \
    }
#define MERGE(p, a0, a1)                                                    \
    {                                                                       \
        float nm = fmaxf(m, p);                                             \
        float sc = __expf(m - nm);                                          \
        float e  = __expf((p) - nm);                                        \
        d = d * sc + e;                                                     \
        acc0 = acc0 * sc + e * (a0);                                        \
        acc1 = acc1 * sc + e * (a1);                                        \
        m = nm;                                                             \
    }

    int k = 0;
    for (; k + 2 <= cnt; k += 2) {
        const int s0 = sorted_src[start + k];
        const int s1 = sorted_src[start + k + 1];
        const ushort2 v0 = xl2[(size_t)s0 * 64 + lane];
        const ushort2 v1 = xl2[(size_t)s1 * 64 + lane];
        const float a00 = bf2f(v0.x), a01 = bf2f(v0.y);
        const float a10 = bf2f(v1.x), a11 = bf2f(v1.y);
        float p0, p1;
        SCORE(a00, a01, p0);
        SCORE(a10, a11, p1);
#pragma unroll
        for (int off = 16; off; off >>= 1) {
            p0 += __shfl_xor(p0, off);
            p1 += __shfl_xor(p1, off);
        }
        MERGE(p0, a00, a01);
        MERGE(p1, a10, a11);
    }
    if (k < cnt) {
        const int s0 = sorted_src[start + k];
        const ushort2 v0 = xl2[(size_t)s0 * 64 + lane];
        const float a00 = bf2f(v0.x), a01 = bf2f(v0.y);
        float p0;
        SCORE(a00, a01, p0);
#pragma unroll
        for (int off = 16; off; off >>= 1) p0 += __shfl_xor(p0, off);
        MERGE(p0, a00, a01);
    }

    const float2 b2 = ((const float2*)bias)[lane];
    float2 o;
    o.x = acc0 / d + b2.x;
    o.y = acc1 / d + b2.y;
    ((float2*)out)[(size_t)node * 64 + lane] = o;
}

extern "C" void kernel_launch(void* const* d_in, const int* in_sizes, int n_in,
                              void* d_out, int out_size, void* d_ws, size_t ws_size,
                              hipStream_t stream) {
    const float* x    = (const float*)d_in[0];
    const int*   ei   = (const int*)d_in[1];
    const float* Wl   = (const float*)d_in[2];
    const float* Wr   = (const float*)d_in[3];
    const float* att  = (const float*)d_in[4];
    const float* bias = (const float*)d_in[5];
    float* out = (float*)d_out;

    const int E  = in_sizes[1] / 2;
    const int ET = E + T_NODES;

    // workspace layout
    ushort_t* xl = (ushort_t*)d_ws;                        // T*128 bf16
    ushort_t* xr = xl + (size_t)T_NODES * HC;              // T*128 bf16
    int* sorted_src = (int*)(xr + (size_t)T_NODES * HC);   // ET int
    unsigned* counts   = (unsigned*)(sorted_src + ET);     // T
    unsigned* offs     = counts + T_NODES;                 // T
    unsigned* cursor   = offs + T_NODES;                   // T
    unsigned* partials = cursor + T_NODES;                 // 128

    hipMemsetAsync(counts, 0, (size_t)T_NODES * sizeof(unsigned), stream);

    gemm_lr<<<T_NODES / 32, 256, 0, stream>>>(x, Wl, Wr, xl, xr);

    int eblocks = (ET + 255) / 256;
    hist_dst<<<eblocks, 256, 0, stream>>>(ei, counts, E, ET);
    scan_tiles<<<T_NODES / 1024, 256, 0, stream>>>(counts, offs, partials);
    scan_partials<<<1, 128, 0, stream>>>(partials);
    finalize_offs<<<T_NODES / 256, 256, 0, stream>>>(offs, partials, cursor);
    scatter_edges<<<eblocks, 256, 0, stream>>>(ei, cursor, sorted_src, E, ET);

    fused_aggr<<<T_NODES / 4, 256, 0, stream>>>(xl, xr, sorted_src, offs, counts,
                                                att, bias, out);
}

// Round 4
// 219.414 us; speedup vs baseline: 3.8790x; 1.3033x over previous
//
#include <hip/hip_runtime.h>
#include <hip/hip_bf16.h>

#define T_NODES (64 * 2048)   // G*N = 131072
#define CIN 64
#define HC 128                // HEADS * C_OUT
#define NEG_SLOPE 0.2f
#define GEMM_BLOCKS (T_NODES / 64)   // BM=64 -> 2048 blocks

typedef unsigned short ushort_t;
typedef __attribute__((ext_vector_type(8))) short bf16x8;
typedef __attribute__((ext_vector_type(4))) float f32x4;

__device__ __forceinline__ ushort_t f2bf(float x) {
    unsigned u = __float_as_uint(x);
    u += 0x7fffu + ((u >> 16) & 1u);   // RNE
    return (ushort_t)(u >> 16);
}
__device__ __forceinline__ float bf2f(ushort_t b) {
    return __uint_as_float(((unsigned)b) << 16);
}

// ---- Kernel A: MFMA gemm (xl = x@W_l, xr = x@W_r, bf16 out) + fused dst-histogram.
// Blocks [0, GEMM_BLOCKS): gemm, BM=64 rows each. Blocks >= GEMM_BLOCKS: histogram.
__global__ __launch_bounds__(256) void gemm_hist(const float* __restrict__ x,
                                                 const float* __restrict__ Wl,
                                                 const float* __restrict__ Wr,
                                                 ushort_t* __restrict__ xl,
                                                 ushort_t* __restrict__ xr,
                                                 const int* __restrict__ ei,
                                                 unsigned* __restrict__ counts,
                                                 int E, int ET) {
    __shared__ uint4 lds4[2560];   // 40 KB: xs[64][64]bf16 (8KB) + wsT[256][64]bf16 (32KB)
    const int tid = threadIdx.x;

    if (blockIdx.x >= GEMM_BLOCKS) {
        // ---- histogram branch: 1024 edges per block ----
        const int b = blockIdx.x - GEMM_BLOCKS;
#pragma unroll
        for (int e = 0; e < 4; ++e) {
            int i = b * 1024 + e * 256 + tid;
            if (i < ET) {
                int dst = (i < E) ? ei[E + i] : (i - E);
                atomicAdd(&counts[dst], 1u);
            }
        }
        return;
    }

    char* abase = (char*)lds4;          // xs: row r (0..63), 128B/row, XOR-swizzled
    char* wbase = (char*)lds4 + 8192;   // wsT: row n (0..255), 128B/row (k-contiguous)
    const int row0 = blockIdx.x * 64;

    // stage x tile: thread t -> row r = t>>2, 16 cols starting c4*16
    {
        const int r = tid >> 2, c4 = tid & 3;
        const float4* xp = (const float4*)(x + (size_t)(row0 + r) * CIN + c4 * 16);
        float4 f0 = xp[0], f1 = xp[1], f2 = xp[2], f3 = xp[3];
        union { ushort_t u[16]; uint4 v[2]; } pk;
        const float s[16] = {f0.x,f0.y,f0.z,f0.w, f1.x,f1.y,f1.z,f1.w,
                             f2.x,f2.y,f2.z,f2.w, f3.x,f3.y,f3.z,f3.w};
#pragma unroll
        for (int j = 0; j < 16; ++j) pk.u[j] = f2bf(s[j]);
        const int sw = (r & 7) << 4;
        *(uint4*)(abase + r * 128 + ((c4 * 32)      ^ sw)) = pk.v[0];
        *(uint4*)(abase + r * 128 + ((c4 * 32 + 16) ^ sw)) = pk.v[1];
    }
    // stage W transposed: thread t -> output row n = t (cols of W), 64 k values
    {
        const int n = tid;
        const float* Wsrc = ((n < HC) ? Wl : Wr) + (n & (HC - 1));
        const int sw = (n & 7) << 4;
#pragma unroll
        for (int cc = 0; cc < 8; ++cc) {
            union { ushort_t u[8]; uint4 v; } pk;
#pragma unroll
            for (int j = 0; j < 8; ++j) pk.u[j] = f2bf(Wsrc[(cc * 8 + j) * HC]);
            *(uint4*)(wbase + n * 128 + ((cc * 16) ^ sw)) = pk.v;
        }
    }
    __syncthreads();

    const int wave = tid >> 6;
    const int lane = tid & 63;
    const int ar = lane & 15;
    const int kb = lane >> 4;

    bf16x8 afr[2][4], bfr[2][4];
#pragma unroll
    for (int kk = 0; kk < 2; ++kk) {
#pragma unroll
        for (int rt = 0; rt < 4; ++rt) {
            const int r = rt * 16 + ar;
            afr[kk][rt] = *(bf16x8*)(abase + r * 128 + ((kk * 64 + kb * 16) ^ ((r & 7) << 4)));
        }
#pragma unroll
        for (int ct = 0; ct < 4; ++ct) {
            const int n = wave * 64 + ct * 16 + ar;
            bfr[kk][ct] = *(bf16x8*)(wbase + n * 128 + ((kk * 64 + kb * 16) ^ ((n & 7) << 4)));
        }
    }

    f32x4 acc[4][4];
#pragma unroll
    for (int rt = 0; rt < 4; ++rt)
#pragma unroll
        for (int ct = 0; ct < 4; ++ct) acc[rt][ct] = (f32x4){0.f, 0.f, 0.f, 0.f};

#pragma unroll
    for (int kk = 0; kk < 2; ++kk)
#pragma unroll
        for (int rt = 0; rt < 4; ++rt)
#pragma unroll
            for (int ct = 0; ct < 4; ++ct)
                acc[rt][ct] = __builtin_amdgcn_mfma_f32_16x16x32_bf16(
                    afr[kk][rt], bfr[kk][ct], acc[rt][ct], 0, 0, 0);

    // C/D layout (verified): col = lane&15, row = (lane>>4)*4 + reg
    ushort_t* op = (wave < 2) ? xl : xr;
    const int colbase = (wave & 1) * 64 + ar;
    const int rowoff = (lane >> 4) * 4;
#pragma unroll
    for (int rt = 0; rt < 4; ++rt)
#pragma unroll
        for (int ct = 0; ct < 4; ++ct)
#pragma unroll
            for (int j = 0; j < 4; ++j)
                op[(size_t)(row0 + rt * 16 + rowoff + j) * HC + colbase + ct * 16] =
                    f2bf(acc[rt][ct][j]);
}

// ---- step 2a: per-tile (1024 entries) exclusive scan; tile sums -> partials ----
__global__ __launch_bounds__(256) void scan_tiles(const unsigned* __restrict__ counts,
                                                  unsigned* __restrict__ offs,
                                                  unsigned* __restrict__ partials) {
    __shared__ unsigned s[256];
    const int t = threadIdx.x;
    const int base = blockIdx.x * 1024 + t * 4;
    uint4 c = *(const uint4*)(counts + base);
    unsigned mysum = c.x + c.y + c.z + c.w;
    s[t] = mysum;
    __syncthreads();
    for (int off = 1; off < 256; off <<= 1) {
        unsigned v = (t >= off) ? s[t - off] : 0u;
        __syncthreads();
        s[t] += v;
        __syncthreads();
    }
    unsigned excl = s[t] - mysum;
    uint4 o;
    o.x = excl;
    o.y = excl + c.x;
    o.z = o.y + c.y;
    o.w = o.z + c.z;
    *(uint4*)(offs + base) = o;
    if (t == 255) partials[blockIdx.x] = s[255];
}

// ---- step 2b: exclusive scan of the 128 tile sums ----
__global__ void scan_partials(unsigned* __restrict__ partials) {
    __shared__ unsigned s[128];
    int t = threadIdx.x;
    unsigned v = partials[t];
    s[t] = v;
    __syncthreads();
    for (int off = 1; off < 128; off <<= 1) {
        unsigned u = (t >= off) ? s[t - off] : 0u;
        __syncthreads();
        s[t] += u;
        __syncthreads();
    }
    partials[t] = s[t] - v;   // exclusive
}

// ---- step 2c: add tile bases; final offsets + mutable cursors ----
__global__ void finalize_offs(unsigned* __restrict__ offs,
                              const unsigned* __restrict__ partials,
                              unsigned* __restrict__ cursor) {
    int i = blockIdx.x * 256 + threadIdx.x;
    unsigned v = offs[i] + partials[i >> 10];
    offs[i] = v;
    cursor[i] = v;
}

// ---- step 3: scatter src ids into dst-sorted order ----
__global__ void scatter_edges(const int* __restrict__ ei, unsigned* __restrict__ cursor,
                              int* __restrict__ sorted_src, int E, int ET) {
    int i = blockIdx.x * 256 + threadIdx.x;
    if (i >= ET) return;
    int src, dst;
    if (i < E) { src = ei[i]; dst = ei[E + i]; }
    else       { src = dst = i - E; }
    unsigned pos = atomicAdd(&cursor[dst], 1u);
    sorted_src[pos] = src;
}

// ---- Kernel B: fused score + softmax (no max subtraction; scores bounded) + aggregate.
// One wave per node. Lane owns cols {2*lane, 2*lane+1}; lanes 0-31 head 0, 32-63 head 1.
__global__ __launch_bounds__(256) void fused_aggr(const ushort_t* __restrict__ xl,
                                                  const ushort_t* __restrict__ xr,
                                                  const int* __restrict__ sorted_src,
                                                  const unsigned* __restrict__ offs,
                                                  const unsigned* __restrict__ counts,
                                                  const float* __restrict__ att,
                                                  const float* __restrict__ bias,
                                                  float* __restrict__ out) {
    const int lane = threadIdx.x & 63;
    int node = (blockIdx.x * 256 + threadIdx.x) >> 6;
    node = __builtin_amdgcn_readfirstlane(node);

    const float2 att2 = ((const float2*)att)[lane];
    const ushort2 xrv = ((const ushort2*)xr)[(size_t)node * 64 + lane];
    const float xr0 = bf2f(xrv.x), xr1 = bf2f(xrv.y);

    const int start = (int)offs[node];
    const int cnt   = (int)counts[node];
    const ushort2* xl2 = (const ushort2*)xl;

    float d = 0.f, acc0 = 0.f, acc1 = 0.f;

#define SCORE(a0, a1, p)                                                    \
    {                                                                       \
        float h0 = (a0) + xr0; h0 = h0 > 0.f ? h0 : NEG_SLOPE * h0;         \
        float h1 = (a1) + xr1; h1 = h1 > 0.f ? h1 : NEG_SLOPE * h1;         \
        p = att2.x * h0 + att2.y * h1;                                      \
    }
#define MERGE(p, a0, a1)                                                    \
    {                                                                       \
        float e = __expf(p);                                                \
        d += e;                                                             \
        acc0 += e * (a0);                                                   \
        acc1 += e * (a1);                                                   \
    }

    int k = 0;
    for (; k + 4 <= cnt; k += 4) {
        const int s0 = sorted_src[start + k];
        const int s1 = sorted_src[start + k + 1];
        const int s2 = sorted_src[start + k + 2];
        const int s3 = sorted_src[start + k + 3];
        const ushort2 v0 = xl2[(size_t)s0 * 64 + lane];
        const ushort2 v1 = xl2[(size_t)s1 * 64 + lane];
        const ushort2 v2 = xl2[(size_t)s2 * 64 + lane];
        const ushort2 v3 = xl2[(size_t)s3 * 64 + lane];
        const float a00 = bf2f(v0.x), a01 = bf2f(v0.y);
        const float a10 = bf2f(v1.x), a11 = bf2f(v1.y);
        const float a20 = bf2f(v2.x), a21 = bf2f(v2.y);
        const float a30 = bf2f(v3.x), a31 = bf2f(v3.y);
        float p0, p1, p2, p3;
        SCORE(a00, a01, p0);
        SCORE(a10, a11, p1);
        SCORE(a20, a21, p2);
        SCORE(a30, a31, p3);
#pragma unroll
        for (int off = 16; off; off >>= 1) {
            p0 += __shfl_xor(p0, off);
            p1 += __shfl_xor(p1, off);
            p2 += __shfl_xor(p2, off);
            p3 += __shfl_xor(p3, off);
        }
        MERGE(p0, a00, a01);
        MERGE(p1, a10, a11);
        MERGE(p2, a20, a21);
        MERGE(p3, a30, a31);
    }
    for (; k < cnt; ++k) {
        const int s0 = sorted_src[start + k];
        const ushort2 v0 = xl2[(size_t)s0 * 64 + lane];
        const float a00 = bf2f(v0.x), a01 = bf2f(v0.y);
        float p0;
        SCORE(a00, a01, p0);
#pragma unroll
        for (int off = 16; off; off >>= 1) p0 += __shfl_xor(p0, off);
        MERGE(p0, a00, a01);
    }

    const float2 b2 = ((const float2*)bias)[lane];
    float2 o;
    o.x = acc0 / d + b2.x;
    o.y = acc1 / d + b2.y;
    ((float2*)out)[(size_t)node * 64 + lane] = o;
}

extern "C" void kernel_launch(void* const* d_in, const int* in_sizes, int n_in,
                              void* d_out, int out_size, void* d_ws, size_t ws_size,
                              hipStream_t stream) {
    const float* x    = (const float*)d_in[0];
    const int*   ei   = (const int*)d_in[1];
    const float* Wl   = (const float*)d_in[2];
    const float* Wr   = (const float*)d_in[3];
    const float* att  = (const float*)d_in[4];
    const float* bias = (const float*)d_in[5];
    float* out = (float*)d_out;

    const int E  = in_sizes[1] / 2;
    const int ET = E + T_NODES;

    // workspace layout
    ushort_t* xl = (ushort_t*)d_ws;                        // T*128 bf16
    ushort_t* xr = xl + (size_t)T_NODES * HC;              // T*128 bf16
    int* sorted_src = (int*)(xr + (size_t)T_NODES * HC);   // ET int
    unsigned* counts   = (unsigned*)(sorted_src + ET);     // T
    unsigned* offs     = counts + T_NODES;                 // T
    unsigned* cursor   = offs + T_NODES;                   // T
    unsigned* partials = cursor + T_NODES;                 // 128

    hipMemsetAsync(counts, 0, (size_t)T_NODES * sizeof(unsigned), stream);

    const int histBlocks = (ET + 1023) / 1024;
    gemm_hist<<<GEMM_BLOCKS + histBlocks, 256, 0, stream>>>(x, Wl, Wr, xl, xr,
                                                            ei, counts, E, ET);

    scan_tiles<<<T_NODES / 1024, 256, 0, stream>>>(counts, offs, partials);
    scan_partials<<<1, 128, 0, stream>>>(partials);
    finalize_offs<<<T_NODES / 256, 256, 0, stream>>>(offs, partials, cursor);
    int eblocks = (ET + 255) / 256;
    scatter_edges<<<eblocks, 256, 0, stream>>>(ei, cursor, sorted_src, E, ET);

    fused_aggr<<<T_NODES / 4, 256, 0, stream>>>(xl, xr, sorted_src, offs, counts,
                                                att, bias, out);
}

// Round 5
// 163.975 us; speedup vs baseline: 5.1905x; 1.3381x over previous
//
#include <hip/hip_runtime.h>
#include <hip/hip_bf16.h>

#define T_NODES (64 * 2048)   // G*N = 131072
#define CIN 64
#define HC 128                // HEADS * C_OUT
#define NEG_SLOPE 0.2f
#define GEMM_BLOCKS (T_NODES / 64)   // BM=64 -> 2048 blocks

typedef unsigned short ushort_t;
typedef __attribute__((ext_vector_type(8))) short bf16x8;
typedef __attribute__((ext_vector_type(4))) float f32x4;

__device__ __forceinline__ ushort_t f2bf(float x) {
    unsigned u = __float_as_uint(x);
    u += 0x7fffu + ((u >> 16) & 1u);   // RNE
    return (ushort_t)(u >> 16);
}
__device__ __forceinline__ float bf2f(ushort_t b) {
    return __uint_as_float(((unsigned)b) << 16);
}

// ---- Kernel 0: one-time W transpose + f32->bf16 + XOR-swizzle into global WtSwz.
// WtSwz layout == the gemm's LDS wsT layout: row n (0..255) = output col
// (n<128 -> W_l col n, else W_r col n-128), 128 B/row of 64 bf16 k-values,
// 16-B chunk cc at byte ((cc*16) ^ ((n&7)<<4)).
__global__ void prep_w(const float* __restrict__ Wl, const float* __restrict__ Wr,
                       uint4* __restrict__ wt) {
    const int t = blockIdx.x * 256 + threadIdx.x;   // 0..2047
    const int n = t & 255, cc = t >> 8;
    const float* Wsrc = ((n < HC) ? Wl : Wr) + (n & (HC - 1));
    union { ushort_t u[8]; uint4 v; } pk;
#pragma unroll
    for (int j = 0; j < 8; ++j) pk.u[j] = f2bf(Wsrc[(cc * 8 + j) * HC]);
    const int sw = (n & 7) << 4;
    *(uint4*)((char*)wt + n * 128 + ((cc * 16) ^ sw)) = pk.v;
}

// ---- Kernel A: MFMA gemm (xl = x@W_l, xr = x@W_r, bf16 out) + fused dst-histogram.
// Blocks [0, histBlocks): histogram (runs first, overlaps gemm). Rest: gemm, BM=64.
__global__ __launch_bounds__(256) void gemm_hist(const float* __restrict__ x,
                                                 const uint4* __restrict__ wt,
                                                 ushort_t* __restrict__ xl,
                                                 ushort_t* __restrict__ xr,
                                                 const int* __restrict__ ei,
                                                 unsigned* __restrict__ counts,
                                                 ushort_t* __restrict__ rank,
                                                 int E, int ET, int histBlocks) {
    __shared__ uint4 lds4[2560];   // 40 KB: xs[64][64]bf16 (8KB) + wsT[256][64]bf16 (32KB)
    const int tid = threadIdx.x;

    if (blockIdx.x < histBlocks) {
        // ---- histogram branch: 1024 edges per block; rank = old count ----
        const int b = blockIdx.x;
#pragma unroll
        for (int e = 0; e < 4; ++e) {
            int i = b * 1024 + e * 256 + tid;
            if (i < ET) {
                int dst = (i < E) ? ei[E + i] : (i - E);
                rank[i] = (ushort_t)atomicAdd(&counts[dst], 1u);
            }
        }
        return;
    }

    char* abase = (char*)lds4;          // xs: row r (0..63), 128B/row, XOR-swizzled
    char* wbase = (char*)lds4 + 8192;   // wsT: row n (0..255), 128B/row (k-contiguous)
    const int row0 = (blockIdx.x - histBlocks) * 64;

    // stage x tile: thread t -> row r = t>>2, 16 cols starting c4*16
    {
        const int r = tid >> 2, c4 = tid & 3;
        const float4* xp = (const float4*)(x + (size_t)(row0 + r) * CIN + c4 * 16);
        float4 f0 = xp[0], f1 = xp[1], f2 = xp[2], f3 = xp[3];
        union { ushort_t u[16]; uint4 v[2]; } pk;
        const float s[16] = {f0.x,f0.y,f0.z,f0.w, f1.x,f1.y,f1.z,f1.w,
                             f2.x,f2.y,f2.z,f2.w, f3.x,f3.y,f3.z,f3.w};
#pragma unroll
        for (int j = 0; j < 16; ++j) pk.u[j] = f2bf(s[j]);
        const int sw = (r & 7) << 4;
        *(uint4*)(abase + r * 128 + ((c4 * 32)      ^ sw)) = pk.v[0];
        *(uint4*)(abase + r * 128 + ((c4 * 32 + 16) ^ sw)) = pk.v[1];
    }
    // stage W: straight 32 KB coalesced copy of pre-swizzled WtSwz
    {
#pragma unroll
        for (int q = 0; q < 8; ++q)
            lds4[512 + q * 256 + tid] = wt[q * 256 + tid];
    }
    __syncthreads();

    const int wave = tid >> 6;
    const int lane = tid & 63;
    const int ar = lane & 15;
    const int kb = lane >> 4;

    bf16x8 afr[2][4], bfr[2][4];
#pragma unroll
    for (int kk = 0; kk < 2; ++kk) {
#pragma unroll
        for (int rt = 0; rt < 4; ++rt) {
            const int r = rt * 16 + ar;
            afr[kk][rt] = *(bf16x8*)(abase + r * 128 + ((kk * 64 + kb * 16) ^ ((r & 7) << 4)));
        }
#pragma unroll
        for (int ct = 0; ct < 4; ++ct) {
            const int n = wave * 64 + ct * 16 + ar;
            bfr[kk][ct] = *(bf16x8*)(wbase + n * 128 + ((kk * 64 + kb * 16) ^ ((n & 7) << 4)));
        }
    }

    f32x4 acc[4][4];
#pragma unroll
    for (int rt = 0; rt < 4; ++rt)
#pragma unroll
        for (int ct = 0; ct < 4; ++ct) acc[rt][ct] = (f32x4){0.f, 0.f, 0.f, 0.f};

#pragma unroll
    for (int kk = 0; kk < 2; ++kk)
#pragma unroll
        for (int rt = 0; rt < 4; ++rt)
#pragma unroll
            for (int ct = 0; ct < 4; ++ct)
                acc[rt][ct] = __builtin_amdgcn_mfma_f32_16x16x32_bf16(
                    afr[kk][rt], bfr[kk][ct], acc[rt][ct], 0, 0, 0);

    // C/D layout (verified): col = lane&15, row = (lane>>4)*4 + reg
    ushort_t* op = (wave < 2) ? xl : xr;
    const int colbase = (wave & 1) * 64 + ar;
    const int rowoff = (lane >> 4) * 4;
#pragma unroll
    for (int rt = 0; rt < 4; ++rt)
#pragma unroll
        for (int ct = 0; ct < 4; ++ct)
#pragma unroll
            for (int j = 0; j < 4; ++j)
                op[(size_t)(row0 + rt * 16 + rowoff + j) * HC + colbase + ct * 16] =
                    f2bf(acc[rt][ct][j]);
}

// ---- step 2a: per-tile (1024 entries) exclusive scan; tile sums -> partials ----
__global__ __launch_bounds__(256) void scan_tiles(const unsigned* __restrict__ counts,
                                                  unsigned* __restrict__ offs,
                                                  unsigned* __restrict__ partials) {
    __shared__ unsigned s[256];
    const int t = threadIdx.x;
    const int base = blockIdx.x * 1024 + t * 4;
    uint4 c = *(const uint4*)(counts + base);
    unsigned mysum = c.x + c.y + c.z + c.w;
    s[t] = mysum;
    __syncthreads();
    for (int off = 1; off < 256; off <<= 1) {
        unsigned v = (t >= off) ? s[t - off] : 0u;
        __syncthreads();
        s[t] += v;
        __syncthreads();
    }
    unsigned excl = s[t] - mysum;
    uint4 o;
    o.x = excl;
    o.y = excl + c.x;
    o.z = o.y + c.y;
    o.w = o.z + c.z;
    *(uint4*)(offs + base) = o;
    if (t == 255) partials[blockIdx.x] = s[255];
}

// ---- step 2b: add tile bases (folds the partials-scan into each block) ----
__global__ __launch_bounds__(256) void finalize_offs(unsigned* __restrict__ offs,
                                                     const unsigned* __restrict__ partials) {
    __shared__ unsigned s[128];
    const int t = threadIdx.x;
    const int tile = blockIdx.x >> 2;       // this block's 256 entries share one tile
    if (t < 128) s[t] = (t < tile) ? partials[t] : 0u;
    __syncthreads();
    for (int off = 64; off; off >>= 1) {
        if (t < off) s[t] += s[t + off];
        __syncthreads();
    }
    const unsigned base = s[0];
    const int i = blockIdx.x * 256 + t;
    offs[i] += base;
}

// ---- step 3: scatter src ids into dst-sorted order (atomic-free) ----
__global__ void scatter_edges(const int* __restrict__ ei,
                              const unsigned* __restrict__ offs,
                              const ushort_t* __restrict__ rank,
                              int* __restrict__ sorted_src, int E, int ET) {
    int i = blockIdx.x * 256 + threadIdx.x;
    if (i >= ET) return;
    int src, dst;
    if (i < E) { src = ei[i]; dst = ei[E + i]; }
    else       { src = dst = i - E; }
    sorted_src[offs[dst] + rank[i]] = src;
}

// ---- Kernel B: fused score + softmax (no max subtraction; scores bounded) + aggregate.
// One wave per node. Lane owns cols {2*lane, 2*lane+1}; lanes 0-31 head 0, 32-63 head 1.
__global__ __launch_bounds__(256) void fused_aggr(const ushort_t* __restrict__ xl,
                                                  const ushort_t* __restrict__ xr,
                                                  const int* __restrict__ sorted_src,
                                                  const unsigned* __restrict__ offs,
                                                  const unsigned* __restrict__ counts,
                                                  const float* __restrict__ att,
                                                  const float* __restrict__ bias,
                                                  float* __restrict__ out) {
    const int lane = threadIdx.x & 63;
    int node = (blockIdx.x * 256 + threadIdx.x) >> 6;
    node = __builtin_amdgcn_readfirstlane(node);

    const float2 att2 = ((const float2*)att)[lane];
    const ushort2 xrv = ((const ushort2*)xr)[(size_t)node * 64 + lane];
    const float xr0 = bf2f(xrv.x), xr1 = bf2f(xrv.y);

    const int start = (int)offs[node];
    const int cnt   = (int)counts[node];
    const ushort2* xl2 = (const ushort2*)xl;

    float d = 0.f, acc0 = 0.f, acc1 = 0.f;

#define SCORE(a0, a1, p)                                                    \
    {                                                                       \
        float h0 = (a0) + xr0; h0 = h0 > 0.f ? h0 : NEG_SLOPE * h0;         \
        float h1 = (a1) + xr1; h1 = h1 > 0.f ? h1 : NEG_SLOPE * h1;         \
        p = att2.x * h0 + att2.y * h1;                                      \
    }
#define MERGE(p, a0, a1)                                                    \
    {                                                                       \
        float e = __expf(p);                                                \
        d += e;                                                             \
        acc0 += e * (a0);                                                   \
        acc1 += e * (a1);                                                   \
    }

    int k = 0;
    for (; k + 4 <= cnt; k += 4) {
        const int s0 = sorted_src[start + k];
        const int s1 = sorted_src[start + k + 1];
        const int s2 = sorted_src[start + k + 2];
        const int s3 = sorted_src[start + k + 3];
        const ushort2 v0 = xl2[(size_t)s0 * 64 + lane];
        const ushort2 v1 = xl2[(size_t)s1 * 64 + lane];
        const ushort2 v2 = xl2[(size_t)s2 * 64 + lane];
        const ushort2 v3 = xl2[(size_t)s3 * 64 + lane];
        const float a00 = bf2f(v0.x), a01 = bf2f(v0.y);
        const float a10 = bf2f(v1.x), a11 = bf2f(v1.y);
        const float a20 = bf2f(v2.x), a21 = bf2f(v2.y);
        const float a30 = bf2f(v3.x), a31 = bf2f(v3.y);
        float p0, p1, p2, p3;
        SCORE(a00, a01, p0);
        SCORE(a10, a11, p1);
        SCORE(a20, a21, p2);
        SCORE(a30, a31, p3);
#pragma unroll
        for (int off = 16; off; off >>= 1) {
            p0 += __shfl_xor(p0, off);
            p1 += __shfl_xor(p1, off);
            p2 += __shfl_xor(p2, off);
            p3 += __shfl_xor(p3, off);
        }
        MERGE(p0, a00, a01);
        MERGE(p1, a10, a11);
        MERGE(p2, a20, a21);
        MERGE(p3, a30, a31);
    }
    for (; k < cnt; ++k) {
        const int s0 = sorted_src[start + k];
        const ushort2 v0 = xl2[(size_t)s0 * 64 + lane];
        const float a00 = bf2f(v0.x), a01 = bf2f(v0.y);
        float p0;
        SCORE(a00, a01, p0);
#pragma unroll
        for (int off = 16; off; off >>= 1) p0 += __shfl_xor(p0, off);
        MERGE(p0, a00, a01);
    }

    const float2 b2 = ((const float2*)bias)[lane];
    float2 o;
    o.x = acc0 / d + b2.x;
    o.y = acc1 / d + b2.y;
    ((float2*)out)[(size_t)node * 64 + lane] = o;
}

extern "C" void kernel_launch(void* const* d_in, const int* in_sizes, int n_in,
                              void* d_out, int out_size, void* d_ws, size_t ws_size,
                              hipStream_t stream) {
    const float* x    = (const float*)d_in[0];
    const int*   ei   = (const int*)d_in[1];
    const float* Wl   = (const float*)d_in[2];
    const float* Wr   = (const float*)d_in[3];
    const float* att  = (const float*)d_in[4];
    const float* bias = (const float*)d_in[5];
    float* out = (float*)d_out;

    const int E  = in_sizes[1] / 2;
    const int ET = E + T_NODES;

    // workspace layout
    ushort_t* xl = (ushort_t*)d_ws;                        // T*128 bf16
    ushort_t* xr = xl + (size_t)T_NODES * HC;              // T*128 bf16
    int* sorted_src = (int*)(xr + (size_t)T_NODES * HC);   // ET int
    unsigned* counts   = (unsigned*)(sorted_src + ET);     // T
    unsigned* offs     = counts + T_NODES;                 // T
    unsigned* partials = offs + T_NODES;                   // 128
    ushort_t* rank     = (ushort_t*)(partials + 128);      // ET u16
    uint4* wt          = (uint4*)(rank + ((ET + 7) & ~7)); // 32 KB, 16B-aligned

    hipMemsetAsync(counts, 0, (size_t)T_NODES * sizeof(unsigned), stream);

    prep_w<<<8, 256, 0, stream>>>(Wl, Wr, wt);

    const int histBlocks = (ET + 1023) / 1024;
    gemm_hist<<<histBlocks + GEMM_BLOCKS, 256, 0, stream>>>(x, wt, xl, xr,
                                                            ei, counts, rank,
                                                            E, ET, histBlocks);

    scan_tiles<<<T_NODES / 1024, 256, 0, stream>>>(counts, offs, partials);
    finalize_offs<<<T_NODES / 256, 256, 0, stream>>>(offs, partials);
    int eblocks = (ET + 255) / 256;
    scatter_edges<<<eblocks, 256, 0, stream>>>(ei, offs, rank, sorted_src, E, ET);

    fused_aggr<<<T_NODES / 4, 256, 0, stream>>>(xl, xr, sorted_src, offs, counts,
                                                att, bias, out);
}

// Round 6
// 163.712 us; speedup vs baseline: 5.1988x; 1.0016x over previous
//
#include <hip/hip_runtime.h>
#include <hip/hip_bf16.h>

#define T_NODES (64 * 2048)   // G*N = 131072
#define CIN 64
#define HC 128                // HEADS * C_OUT
#define NEG_SLOPE 0.2f
#define GEMM_BLOCKS (T_NODES / 64)   // BM=64 -> 2048 blocks

typedef unsigned short ushort_t;
typedef __attribute__((ext_vector_type(8))) short bf16x8;
typedef __attribute__((ext_vector_type(4))) float f32x4;

__device__ __forceinline__ ushort_t f2bf(float x) {
    unsigned u = __float_as_uint(x);
    u += 0x7fffu + ((u >> 16) & 1u);   // RNE
    return (ushort_t)(u >> 16);
}
__device__ __forceinline__ float bf2f(ushort_t b) {
    return __uint_as_float(((unsigned)b) << 16);
}

// ---- Kernel 0: one-time W transpose + f32->bf16 + XOR-swizzle into global WtSwz.
__global__ void prep_w(const float* __restrict__ Wl, const float* __restrict__ Wr,
                       uint4* __restrict__ wt) {
    const int t = blockIdx.x * 256 + threadIdx.x;   // 0..2047
    const int n = t & 255, cc = t >> 8;
    const float* Wsrc = ((n < HC) ? Wl : Wr) + (n & (HC - 1));
    union { ushort_t u[8]; uint4 v; } pk;
#pragma unroll
    for (int j = 0; j < 8; ++j) pk.u[j] = f2bf(Wsrc[(cc * 8 + j) * HC]);
    const int sw = (n & 7) << 4;
    *(uint4*)((char*)wt + n * 128 + ((cc * 16) ^ sw)) = pk.v;
}

// ---- Kernel A: MFMA gemm (xl = x@W_l, xr = x@W_r, bf16 out) + fused dst-histogram.
__global__ __launch_bounds__(256) void gemm_hist(const float* __restrict__ x,
                                                 const uint4* __restrict__ wt,
                                                 ushort_t* __restrict__ xl,
                                                 ushort_t* __restrict__ xr,
                                                 const int* __restrict__ ei,
                                                 unsigned* __restrict__ counts,
                                                 ushort_t* __restrict__ rank,
                                                 int E, int ET, int histBlocks) {
    __shared__ uint4 lds4[2560];   // 40 KB: xs[64][64]bf16 (8KB) + wsT[256][64]bf16 (32KB)
    const int tid = threadIdx.x;

    if (blockIdx.x < histBlocks) {
        const int b = blockIdx.x;
#pragma unroll
        for (int e = 0; e < 4; ++e) {
            int i = b * 1024 + e * 256 + tid;
            if (i < ET) {
                int dst = (i < E) ? ei[E + i] : (i - E);
                rank[i] = (ushort_t)atomicAdd(&counts[dst], 1u);
            }
        }
        return;
    }

    char* abase = (char*)lds4;          // xs: row r (0..63), 128B/row, XOR-swizzled
    char* wbase = (char*)lds4 + 8192;   // wsT: row n (0..255), 128B/row (k-contiguous)
    const int row0 = (blockIdx.x - histBlocks) * 64;

    {
        const int r = tid >> 2, c4 = tid & 3;
        const float4* xp = (const float4*)(x + (size_t)(row0 + r) * CIN + c4 * 16);
        float4 f0 = xp[0], f1 = xp[1], f2 = xp[2], f3 = xp[3];
        union { ushort_t u[16]; uint4 v[2]; } pk;
        const float s[16] = {f0.x,f0.y,f0.z,f0.w, f1.x,f1.y,f1.z,f1.w,
                             f2.x,f2.y,f2.z,f2.w, f3.x,f3.y,f3.z,f3.w};
#pragma unroll
        for (int j = 0; j < 16; ++j) pk.u[j] = f2bf(s[j]);
        const int sw = (r & 7) << 4;
        *(uint4*)(abase + r * 128 + ((c4 * 32)      ^ sw)) = pk.v[0];
        *(uint4*)(abase + r * 128 + ((c4 * 32 + 16) ^ sw)) = pk.v[1];
    }
    {
#pragma unroll
        for (int q = 0; q < 8; ++q)
            lds4[512 + q * 256 + tid] = wt[q * 256 + tid];
    }
    __syncthreads();

    const int wave = tid >> 6;
    const int lane = tid & 63;
    const int ar = lane & 15;
    const int kb = lane >> 4;

    bf16x8 afr[2][4], bfr[2][4];
#pragma unroll
    for (int kk = 0; kk < 2; ++kk) {
#pragma unroll
        for (int rt = 0; rt < 4; ++rt) {
            const int r = rt * 16 + ar;
            afr[kk][rt] = *(bf16x8*)(abase + r * 128 + ((kk * 64 + kb * 16) ^ ((r & 7) << 4)));
        }
#pragma unroll
        for (int ct = 0; ct < 4; ++ct) {
            const int n = wave * 64 + ct * 16 + ar;
            bfr[kk][ct] = *(bf16x8*)(wbase + n * 128 + ((kk * 64 + kb * 16) ^ ((n & 7) << 4)));
        }
    }

    f32x4 acc[4][4];
#pragma unroll
    for (int rt = 0; rt < 4; ++rt)
#pragma unroll
        for (int ct = 0; ct < 4; ++ct) acc[rt][ct] = (f32x4){0.f, 0.f, 0.f, 0.f};

#pragma unroll
    for (int kk = 0; kk < 2; ++kk)
#pragma unroll
        for (int rt = 0; rt < 4; ++rt)
#pragma unroll
            for (int ct = 0; ct < 4; ++ct)
                acc[rt][ct] = __builtin_amdgcn_mfma_f32_16x16x32_bf16(
                    afr[kk][rt], bfr[kk][ct], acc[rt][ct], 0, 0, 0);

    // C/D layout (verified): col = lane&15, row = (lane>>4)*4 + reg
    ushort_t* op = (wave < 2) ? xl : xr;
    const int colbase = (wave & 1) * 64 + ar;
    const int rowoff = (lane >> 4) * 4;
#pragma unroll
    for (int rt = 0; rt < 4; ++rt)
#pragma unroll
        for (int ct = 0; ct < 4; ++ct)
#pragma unroll
            for (int j = 0; j < 4; ++j)
                op[(size_t)(row0 + rt * 16 + rowoff + j) * HC + colbase + ct * 16] =
                    f2bf(acc[rt][ct][j]);
}

// ---- step 2a: per-tile (1024 entries) exclusive scan; tile sums -> partials ----
__global__ __launch_bounds__(256) void scan_tiles(const unsigned* __restrict__ counts,
                                                  unsigned* __restrict__ offs,
                                                  unsigned* __restrict__ partials) {
    __shared__ unsigned s[256];
    const int t = threadIdx.x;
    const int base = blockIdx.x * 1024 + t * 4;
    uint4 c = *(const uint4*)(counts + base);
    unsigned mysum = c.x + c.y + c.z + c.w;
    s[t] = mysum;
    __syncthreads();
    for (int off = 1; off < 256; off <<= 1) {
        unsigned v = (t >= off) ? s[t - off] : 0u;
        __syncthreads();
        s[t] += v;
        __syncthreads();
    }
    unsigned excl = s[t] - mysum;
    uint4 o;
    o.x = excl;
    o.y = excl + c.x;
    o.z = o.y + c.y;
    o.w = o.z + c.z;
    *(uint4*)(offs + base) = o;
    if (t == 255) partials[blockIdx.x] = s[255];
}

// ---- step 2b: add tile bases (folds the partials-scan into each block) ----
__global__ __launch_bounds__(256) void finalize_offs(unsigned* __restrict__ offs,
                                                     const unsigned* __restrict__ partials) {
    __shared__ unsigned s[128];
    const int t = threadIdx.x;
    const int tile = blockIdx.x >> 2;
    if (t < 128) s[t] = (t < tile) ? partials[t] : 0u;
    __syncthreads();
    for (int off = 64; off; off >>= 1) {
        if (t < off) s[t] += s[t + off];
        __syncthreads();
    }
    const unsigned base = s[0];
    const int i = blockIdx.x * 256 + t;
    offs[i] += base;
}

// ---- step 3: scatter src ids into dst-sorted order (atomic-free) ----
__global__ void scatter_edges(const int* __restrict__ ei,
                              const unsigned* __restrict__ offs,
                              const ushort_t* __restrict__ rank,
                              int* __restrict__ sorted_src, int E, int ET) {
    int i = blockIdx.x * 256 + threadIdx.x;
    if (i >= ET) return;
    int src, dst;
    if (i < E) { src = ei[i]; dst = ei[E + i]; }
    else       { src = dst = i - E; }
    sorted_src[offs[dst] + rank[i]] = src;
}

// ---- Kernel B: fused score + softmax + aggregate. One wave per node. ----
// 4 edges per wave, 8 channels per lane:
//   lane = slot*16 + sub;  slot in [0,4) = edge slot, sub in [0,16), channels sub*8..+8
//   (sub 0-7 -> head 0, sub 8-15 -> head 1; score reduce = 3 shfl over the 8-lane group)
__global__ __launch_bounds__(256) void fused_aggr(const ushort_t* __restrict__ xl,
                                                  const ushort_t* __restrict__ xr,
                                                  const int* __restrict__ sorted_src,
                                                  const unsigned* __restrict__ offs,
                                                  const unsigned* __restrict__ counts,
                                                  const float* __restrict__ att,
                                                  const float* __restrict__ bias,
                                                  float* __restrict__ out) {
    const int tid = threadIdx.x;
    const int lane = tid & 63;
    int node = (blockIdx.x * 256 + tid) >> 6;
    node = __builtin_amdgcn_readfirstlane(node);
    const int slot = lane >> 4;
    const int sub  = lane & 15;
    const int cb   = sub * 8;          // channel base

    // per-lane constants: att, xr slice (8 channels each)
    float attv[8], xrv[8];
    {
        const float4 a0 = *(const float4*)(att + cb);
        const float4 a1 = *(const float4*)(att + cb + 4);
        attv[0]=a0.x; attv[1]=a0.y; attv[2]=a0.z; attv[3]=a0.w;
        attv[4]=a1.x; attv[5]=a1.y; attv[6]=a1.z; attv[7]=a1.w;
        const uint4 xv = *(const uint4*)(xr + (size_t)node * HC + cb);
        const ushort_t* xu = (const ushort_t*)&xv;
#pragma unroll
        for (int j = 0; j < 8; ++j) xrv[j] = bf2f(xu[j]);
    }

    const int start = (int)offs[node];
    const int cnt   = (int)counts[node];
    const int rounds = (cnt + 3) >> 2;

    float acc[8];
#pragma unroll
    for (int j = 0; j < 8; ++j) acc[j] = 0.f;
    float d = 0.f;

    for (int r = 0; r < rounds; ++r) {
        const int k = r * 4 + slot;
        const bool valid = k < cnt;
        const int src = sorted_src[start + (valid ? k : 0)];
        const uint4 v = *(const uint4*)(xl + (size_t)src * HC + cb);
        const ushort_t* vu = (const ushort_t*)&v;
        float a[8];
        float p = 0.f;
#pragma unroll
        for (int j = 0; j < 8; ++j) {
            a[j] = bf2f(vu[j]);
            float z = a[j] + xrv[j];
            float lr = z > 0.f ? z : NEG_SLOPE * z;
            p = __builtin_fmaf(attv[j], lr, p);
        }
        // reduce over the 8-lane channel group (covers this edge's head)
        p += __shfl_xor(p, 1);
        p += __shfl_xor(p, 2);
        p += __shfl_xor(p, 4);
        const float e = valid ? __expf(p) : 0.f;
        d += e;
#pragma unroll
        for (int j = 0; j < 8; ++j) acc[j] = __builtin_fmaf(e, a[j], acc[j]);
    }

    // reduce across the 4 edge slots (xor 16, 32)
#pragma unroll
    for (int off = 16; off <= 32; off <<= 1) {
        d += __shfl_xor(d, off);
#pragma unroll
        for (int j = 0; j < 8; ++j) acc[j] += __shfl_xor(acc[j], off);
    }

    if (slot == 0) {
        const float inv = 1.f / d;
        const float4 b0 = *(const float4*)(bias + cb);
        const float4 b1 = *(const float4*)(bias + cb + 4);
        float4 o0, o1;
        o0.x = acc[0] * inv + b0.x; o0.y = acc[1] * inv + b0.y;
        o0.z = acc[2] * inv + b0.z; o0.w = acc[3] * inv + b0.w;
        o1.x = acc[4] * inv + b1.x; o1.y = acc[5] * inv + b1.y;
        o1.z = acc[6] * inv + b1.z; o1.w = acc[7] * inv + b1.w;
        float* op = out + (size_t)node * HC + cb;
        *(float4*)op = o0;
        *(float4*)(op + 4) = o1;
    }
}

extern "C" void kernel_launch(void* const* d_in, const int* in_sizes, int n_in,
                              void* d_out, int out_size, void* d_ws, size_t ws_size,
                              hipStream_t stream) {
    const float* x    = (const float*)d_in[0];
    const int*   ei   = (const int*)d_in[1];
    const float* Wl   = (const float*)d_in[2];
    const float* Wr   = (const float*)d_in[3];
    const float* att  = (const float*)d_in[4];
    const float* bias = (const float*)d_in[5];
    float* out = (float*)d_out;

    const int E  = in_sizes[1] / 2;
    const int ET = E + T_NODES;

    // workspace layout
    ushort_t* xl = (ushort_t*)d_ws;                        // T*128 bf16
    ushort_t* xr = xl + (size_t)T_NODES * HC;              // T*128 bf16
    int* sorted_src = (int*)(xr + (size_t)T_NODES * HC);   // ET int
    unsigned* counts   = (unsigned*)(sorted_src + ET);     // T
    unsigned* offs     = counts + T_NODES;                 // T
    unsigned* partials = offs + T_NODES;                   // 128
    ushort_t* rank     = (ushort_t*)(partials + 128);      // ET u16
    uint4* wt          = (uint4*)(rank + ((ET + 7) & ~7)); // 32 KB, 16B-aligned

    hipMemsetAsync(counts, 0, (size_t)T_NODES * sizeof(unsigned), stream);

    prep_w<<<8, 256, 0, stream>>>(Wl, Wr, wt);

    const int histBlocks = (ET + 1023) / 1024;
    gemm_hist<<<histBlocks + GEMM_BLOCKS, 256, 0, stream>>>(x, wt, xl, xr,
                                                            ei, counts, rank,
                                                            E, ET, histBlocks);

    scan_tiles<<<T_NODES / 1024, 256, 0, stream>>>(counts, offs, partials);
    finalize_offs<<<T_NODES / 256, 256, 0, stream>>>(offs, partials);
    int eblocks = (ET + 255) / 256;
    scatter_edges<<<eblocks, 256, 0, stream>>>(ei, offs, rank, sorted_src, E, ET);

    fused_aggr<<<T_NODES / 4, 256, 0, stream>>>(xl, xr, sorted_src, offs, counts,
                                                att, bias, out);
}